// Round 6
// baseline (306.833 us; speedup 1.0000x reference)
//
#include <hip/hip_runtime.h>

#define IN_DIM 256
#define U_DIM  512
#define L2E    1.44269504088896340736f

typedef float f32x2 __attribute__((ext_vector_type(2)));
typedef float f32x4 __attribute__((ext_vector_type(4)));

__device__ __forceinline__ f32x2 vfma2(f32x2 a, f32x2 b, f32x2 c) {
    return __builtin_elementwise_fma(a, b, c);
}

__device__ __forceinline__ float exp2scale(float y) {
    // y = t + 1.5*2^23 with t in [-100,14]; bits(y) = 0x4B400000 + round(t)
    // returns float 2^round(t):  ((n mod 512)<<23) + 127<<23  (mod 2^32 arithmetic)
    unsigned s = (__float_as_uint(y) << 23) + 0x3F800000u;
    return __uint_as_float(s);
}

// p_k = 1/(1 + 2^{t_k}) for 4 values held as 2 packed pairs; ONE hw rcp total,
// 2^t via round-to-nearest magic + degree-4 poly in packed (v_pk_*) math.
__device__ __forceinline__ void quad_sig(f32x2 t01, f32x2 t23,
                                         f32x2& p01, f32x2& p23) {
    const float CM = 12582912.0f;          // 1.5 * 2^23
    const float c4 = 0.00961813f, c3 = 0.05550411f,
                c2 = 0.24022651f, c1 = 0.69314718f;
    t01.x = fminf(fmaxf(t01.x, -100.f), 14.f);   // med3; clamp@14 -> |err| <= 6e-5
    t01.y = fminf(fmaxf(t01.y, -100.f), 14.f);
    t23.x = fminf(fmaxf(t23.x, -100.f), 14.f);
    t23.y = fminf(fmaxf(t23.y, -100.f), 14.f);
    f32x2 y01 = t01 + (f32x2)(CM);
    f32x2 y23 = t23 + (f32x2)(CM);
    f32x2 f01 = t01 - (y01 - (f32x2)(CM));       // frac in [-0.5, 0.5]
    f32x2 f23 = t23 - (y23 - (f32x2)(CM));
    f32x2 q01 = vfma2((f32x2)(c4), f01, (f32x2)(c3));
    f32x2 q23 = vfma2((f32x2)(c4), f23, (f32x2)(c3));
    q01 = vfma2(q01, f01, (f32x2)(c2));  q23 = vfma2(q23, f23, (f32x2)(c2));
    q01 = vfma2(q01, f01, (f32x2)(c1));  q23 = vfma2(q23, f23, (f32x2)(c1));
    q01 = vfma2(q01, f01, (f32x2)(1.f)); q23 = vfma2(q23, f23, (f32x2)(1.f));
    f32x2 sc01 = { exp2scale(y01.x), exp2scale(y01.y) };
    f32x2 sc23 = { exp2scale(y23.x), exp2scale(y23.y) };
    f32x2 d01 = vfma2(q01, sc01, (f32x2)(1.f));  // 1 + 2^t
    f32x2 d23 = vfma2(q23, sc23, (f32x2)(1.f));
    float a = d01.x * d01.y, b = d23.x * d23.y;  // <= (1+2^14)^4 ~ 2^56, safe
    float R = __builtin_amdgcn_rcpf(a * b);
    float Ra = R * a, Rb = R * b;
    p01 = (f32x2){ Rb * d01.y, Rb * d01.x };
    p23 = (f32x2){ Ra * d23.y, Ra * d23.x };
}

// ---------- prefuse params ----------
__global__ void k_fuse(const float* __restrict__ mu, const float* __restrict__ sigma,
                       const float* __restrict__ W, const float* __restrict__ erev,
                       const float* __restrict__ smu, const float* __restrict__ ssig,
                       const float* __restrict__ sW, const float* __restrict__ serev,
                       float2* __restrict__ sm2, float* __restrict__ wep,
                       float4* __restrict__ sf4) {
    int i = blockIdx.x * blockDim.x + threadIdx.x;
    const int UU = U_DIM * U_DIM;
    const int SU = IN_DIM * U_DIM;
    if (i < UU) {
        float s = sigma[i] * L2E;
        sm2[i] = make_float2(s, mu[i] * s);
        wep[i] = W[i] * erev[i];
    } else if (i < UU + SU) {
        int j = i - UU;
        float s = ssig[j] * L2E;
        float w = sW[j];
        sf4[j] = make_float4(s, smu[j] * s, w * serev[j], w);
    }
}

// ---------- sensory: tile 8 rows x 32 u; 512 thr = 16 strips x 16 i ----------
__global__ __launch_bounds__(512, 4) void k_sensory(
    const float* __restrict__ inputs, const float* __restrict__ input_w,
    const float* __restrict__ input_b, const float4* __restrict__ sf4,
    float* __restrict__ wnum_s, float* __restrict__ wden_s) {
    __shared__ __align__(16) float xs2[IN_DIM * 8];  // [i][r] interleaved, 8 KB
    __shared__ float red_n[8 * 8 * 32];              // 8 KB
    __shared__ float red_d[8 * 8 * 32];              // 8 KB
    const int tid = threadIdx.x;
    const int b0 = blockIdx.x * 8;
    const int u0 = blockIdx.y * 32;

    #pragma unroll
    for (int k = 0; k < 4; ++k) {
        int idx = tid + k * 512;
        int r = idx >> 8, i = idx & 255;
        xs2[i * 8 + r] = fmaf(inputs[(b0 + r) * IN_DIM + i], input_w[i], input_b[i]);
    }
    __syncthreads();

    const int lane = tid & 63;
    const int w = tid >> 6;
    const int ulh = lane & 31;
    const int ih = lane >> 5;
    const int strip = w * 2 + ih;        // 0..15
    const int u = u0 + ulh;
    const int i0 = strip * 16;

    f32x2 na01 = {0,0}, na23 = {0,0}, na45 = {0,0}, na67 = {0,0};
    f32x2 da01 = {0,0}, da23 = {0,0}, da45 = {0,0}, da67 = {0,0};

    #pragma unroll 2
    for (int ic = 0; ic < 16; ++ic) {
        const int i = i0 + ic;
        const float4 q = sf4[i * U_DIM + u];
        const float sgn = -q.x, ms = q.y, we = q.z, wa = q.w;
        f32x4 va = *reinterpret_cast<const f32x4*>(&xs2[i * 8]);
        f32x4 vb = *reinterpret_cast<const f32x4*>(&xs2[i * 8 + 4]);
        f32x2 p01, p23, p45, p67;
        {
            f32x2 t01 = vfma2((f32x2)(sgn), va.xy, (f32x2)(ms));
            f32x2 t23 = vfma2((f32x2)(sgn), va.zw, (f32x2)(ms));
            quad_sig(t01, t23, p01, p23);
        }
        {
            f32x2 t45 = vfma2((f32x2)(sgn), vb.xy, (f32x2)(ms));
            f32x2 t67 = vfma2((f32x2)(sgn), vb.zw, (f32x2)(ms));
            quad_sig(t45, t67, p45, p67);
        }
        na01 = vfma2((f32x2)(we), p01, na01); da01 = vfma2((f32x2)(wa), p01, da01);
        na23 = vfma2((f32x2)(we), p23, na23); da23 = vfma2((f32x2)(wa), p23, da23);
        na45 = vfma2((f32x2)(we), p45, na45); da45 = vfma2((f32x2)(wa), p45, da45);
        na67 = vfma2((f32x2)(we), p67, na67); da67 = vfma2((f32x2)(wa), p67, da67);
    }

    float nacc[8] = { na01.x, na01.y, na23.x, na23.y, na45.x, na45.y, na67.x, na67.y };
    float dacc[8] = { da01.x, da01.y, da23.x, da23.y, da45.x, da45.y, da67.x, da67.y };
    #pragma unroll
    for (int r = 0; r < 8; ++r) {
        nacc[r] += __shfl_xor(nacc[r], 32);
        dacc[r] += __shfl_xor(dacc[r], 32);
    }
    if (lane < 32) {
        #pragma unroll
        for (int r = 0; r < 8; ++r) {
            red_n[(w * 8 + r) * 32 + ulh] = nacc[r];
            red_d[(w * 8 + r) * 32 + ulh] = dacc[r];
        }
    }
    __syncthreads();
    if (tid < 8 * 32) {
        const int r = tid >> 5, uu = tid & 31;
        float n = 0.f, d = 0.f;
        #pragma unroll
        for (int s = 0; s < 8; ++s) {
            n += red_n[(s * 8 + r) * 32 + uu];
            d += red_d[(s * 8 + r) * 32 + uu];
        }
        wnum_s[(b0 + r) * U_DIM + (u0 + uu)] = n;
        wden_s[(b0 + r) * U_DIM + (u0 + uu)] = d;
    }
}

// ---------- one ODE unfold: tile 8 rows x 32 u; 16 strips x 32 i ----------
__global__ __launch_bounds__(512, 4) void k_unfold(
    const float* __restrict__ vin,
    const float2* __restrict__ sm2, const float* __restrict__ wep,
    const float* __restrict__ wnum_s, const float* __restrict__ wden_s,
    const float* __restrict__ vleak, const float* __restrict__ gleak,
    const float* __restrict__ cm, float* __restrict__ vout) {
    __shared__ __align__(16) float vs2[U_DIM * 8];   // [i][r] interleaved, 16 KB
    __shared__ float red_n[8 * 8 * 32];              // 8 KB
    __shared__ float red_d[8 * 8 * 32];              // 8 KB
    const int tid = threadIdx.x;
    const int b0 = blockIdx.x * 8;
    const int u0 = blockIdx.y * 32;

    #pragma unroll
    for (int k = 0; k < 8; ++k) {
        int idx = tid + k * 512;
        int r = idx >> 9, i = idx & 511;
        vs2[i * 8 + r] = vin[(size_t)b0 * U_DIM + idx];
    }
    __syncthreads();

    const int lane = tid & 63;
    const int w = tid >> 6;
    const int ulh = lane & 31;
    const int ih = lane >> 5;
    const int strip = w * 2 + ih;        // 0..15
    const int u = u0 + ulh;
    const int i0 = strip * 32;

    f32x2 na01 = {0,0}, na23 = {0,0}, na45 = {0,0}, na67 = {0,0};
    f32x2 da01 = {0,0}, da23 = {0,0}, da45 = {0,0}, da67 = {0,0};

    #pragma unroll 2
    for (int ic = 0; ic < 32; ++ic) {
        const int i = i0 + ic;
        const float2 q = sm2[i * U_DIM + u];
        const float we = wep[i * U_DIM + u];
        const float wa = fabsf(we);
        const float sgn = -q.x, ms = q.y;
        f32x4 va = *reinterpret_cast<const f32x4*>(&vs2[i * 8]);
        f32x4 vb = *reinterpret_cast<const f32x4*>(&vs2[i * 8 + 4]);
        f32x2 p01, p23, p45, p67;
        {
            f32x2 t01 = vfma2((f32x2)(sgn), va.xy, (f32x2)(ms));
            f32x2 t23 = vfma2((f32x2)(sgn), va.zw, (f32x2)(ms));
            quad_sig(t01, t23, p01, p23);
        }
        {
            f32x2 t45 = vfma2((f32x2)(sgn), vb.xy, (f32x2)(ms));
            f32x2 t67 = vfma2((f32x2)(sgn), vb.zw, (f32x2)(ms));
            quad_sig(t45, t67, p45, p67);
        }
        na01 = vfma2((f32x2)(we), p01, na01); da01 = vfma2((f32x2)(wa), p01, da01);
        na23 = vfma2((f32x2)(we), p23, na23); da23 = vfma2((f32x2)(wa), p23, da23);
        na45 = vfma2((f32x2)(we), p45, na45); da45 = vfma2((f32x2)(wa), p45, da45);
        na67 = vfma2((f32x2)(we), p67, na67); da67 = vfma2((f32x2)(wa), p67, da67);
    }

    float nacc[8] = { na01.x, na01.y, na23.x, na23.y, na45.x, na45.y, na67.x, na67.y };
    float dacc[8] = { da01.x, da01.y, da23.x, da23.y, da45.x, da45.y, da67.x, da67.y };
    #pragma unroll
    for (int r = 0; r < 8; ++r) {
        nacc[r] += __shfl_xor(nacc[r], 32);
        dacc[r] += __shfl_xor(dacc[r], 32);
    }
    if (lane < 32) {
        #pragma unroll
        for (int r = 0; r < 8; ++r) {
            red_n[(w * 8 + r) * 32 + ulh] = nacc[r];
            red_d[(w * 8 + r) * 32 + ulh] = dacc[r];
        }
    }
    __syncthreads();
    if (tid < 8 * 32) {
        const int r = tid >> 5, uu = tid & 31;
        float n = 0.f, d = 0.f;
        #pragma unroll
        for (int s = 0; s < 8; ++s) {
            n += red_n[(s * 8 + r) * 32 + uu];
            d += red_d[(s * 8 + r) * 32 + uu];
        }
        const int gu = u0 + uu, gb = b0 + r;
        float vold = vs2[gu * 8 + r];
        float gl = gleak[gu], c = cm[gu];
        float num = fmaf(c, vold, fmaf(gl, vleak[gu], n + wnum_s[gb * U_DIM + gu]));
        float den = c + gl + d + wden_s[gb * U_DIM + gu];
        vout[gb * U_DIM + gu] = num * __builtin_amdgcn_rcpf(den);
    }
}

// ---------- fallback (tiny ws): one block per batch row ----------
__global__ __launch_bounds__(512) void k_mono(
    const float* __restrict__ inputs, const float* __restrict__ state,
    const float* __restrict__ input_w, const float* __restrict__ input_b,
    const float* __restrict__ smu, const float* __restrict__ ssig,
    const float* __restrict__ sW, const float* __restrict__ serev,
    const float* __restrict__ mu, const float* __restrict__ sigma,
    const float* __restrict__ W, const float* __restrict__ erev,
    const float* __restrict__ vleak, const float* __restrict__ gleak,
    const float* __restrict__ cm, float* __restrict__ out) {
    __shared__ float xs[IN_DIM];
    __shared__ float vsh[U_DIM];
    const int b = blockIdx.x, u = threadIdx.x;
    if (u < IN_DIM) xs[u] = fmaf(inputs[b * IN_DIM + u], input_w[u], input_b[u]);
    vsh[u] = state[b * U_DIM + u];
    __syncthreads();
    float ns = 0.f, ds = 0.f;
    for (int i = 0; i < IN_DIM; ++i) {
        int pi = i * U_DIM + u;
        float e = __builtin_amdgcn_exp2f((smu[pi] - xs[i]) * (ssig[pi] * L2E));
        float p = __builtin_amdgcn_rcpf(1.f + e);
        float a = sW[pi] * p;
        ns = fmaf(a, serev[pi], ns);
        ds += a;
    }
    const float c = cm[u], gl = gleak[u], glvl = gl * vleak[u];
    for (int t = 0; t < 6; ++t) {
        float n = ns, d = ds;
        for (int i = 0; i < U_DIM; ++i) {
            int pi = i * U_DIM + u;
            float e = __builtin_amdgcn_exp2f((mu[pi] - vsh[i]) * (sigma[pi] * L2E));
            float p = __builtin_amdgcn_rcpf(1.f + e);
            float a = W[pi] * p;
            n = fmaf(a, erev[pi], n);
            d += a;
        }
        float vn = (fmaf(c, vsh[u], glvl) + n) / (c + gl + d);
        __syncthreads();
        vsh[u] = vn;
        __syncthreads();
    }
    out[b * U_DIM + u] = vsh[u];
}

extern "C" void kernel_launch(void* const* d_in, const int* in_sizes, int n_in,
                              void* d_out, int out_size, void* d_ws, size_t ws_size,
                              hipStream_t stream) {
    const float* inputs  = (const float*)d_in[0];
    const float* state   = (const float*)d_in[1];
    const float* input_w = (const float*)d_in[2];
    const float* input_b = (const float*)d_in[3];
    const float* smu     = (const float*)d_in[4];
    const float* ssig    = (const float*)d_in[5];
    const float* sW      = (const float*)d_in[6];
    const float* serev   = (const float*)d_in[7];
    const float* mu      = (const float*)d_in[8];
    const float* sigma   = (const float*)d_in[9];
    const float* W       = (const float*)d_in[10];
    const float* erev    = (const float*)d_in[11];
    const float* vleak   = (const float*)d_in[12];
    const float* gleak   = (const float*)d_in[13];
    const float* cm      = (const float*)d_in[14];
    float* out = (float*)d_out;

    const int B = in_sizes[1] / U_DIM;   // 512
    const size_t BU = (size_t)B * U_DIM;
    const size_t UU = (size_t)U_DIM * U_DIM;
    const size_t SU = (size_t)IN_DIM * U_DIM;
    const size_t need = (3 * BU + 3 * UU + 4 * SU) * sizeof(float);

    if (ws_size >= need) {
        float* f      = (float*)d_ws;
        float* wnum_s = f;
        float* wden_s = f + BU;
        float* vbuf   = f + 2 * BU;
        float2* sm2   = (float2*)(f + 3 * BU);
        float* wep    = f + 3 * BU + 2 * UU;
        float4* sf4   = (float4*)(f + 3 * BU + 3 * UU);

        const int nfuse = (int)(UU + SU);
        k_fuse<<<(nfuse + 255) / 256, 256, 0, stream>>>(mu, sigma, W, erev,
                                                        smu, ssig, sW, serev,
                                                        sm2, wep, sf4);
        dim3 grid(B / 8, U_DIM / 32);    // 64 x 16 = 1024 blocks
        k_sensory<<<grid, 512, 0, stream>>>(inputs, input_w, input_b, sf4, wnum_s, wden_s);
        const float* vin = state;
        float* pong[2] = { vbuf, out };  // ends on out after 6 steps
        for (int t = 0; t < 6; ++t) {
            float* vo = pong[t & 1];
            k_unfold<<<grid, 512, 0, stream>>>(vin, sm2, wep, wnum_s, wden_s,
                                               vleak, gleak, cm, vo);
            vin = vo;
        }
    } else {
        k_mono<<<B, U_DIM, 0, stream>>>(inputs, state, input_w, input_b,
                                        smu, ssig, sW, serev, mu, sigma, W, erev,
                                        vleak, gleak, cm, out);
    }
}

// Round 7
// 227.773 us; speedup vs baseline: 1.3471x; 1.3471x over previous
//
#include <hip/hip_runtime.h>

#define IN_DIM 256
#define U_DIM  512
#define L2E    1.44269504088896340736f

// ---------- prefuse params ----------
// recurrent: sm2 = (sigma*l2e, mu*sigma*l2e), wep = W*erev (W = |wep|, erev=+-1)
// sensory:   sf4 = (sigma*l2e, mu*sigma*l2e, W*erev, W)
__global__ void k_fuse(const float* __restrict__ mu, const float* __restrict__ sigma,
                       const float* __restrict__ W, const float* __restrict__ erev,
                       const float* __restrict__ smu, const float* __restrict__ ssig,
                       const float* __restrict__ sW, const float* __restrict__ serev,
                       float2* __restrict__ sm2, float* __restrict__ wep,
                       float4* __restrict__ sf4) {
    int i = blockIdx.x * blockDim.x + threadIdx.x;
    const int UU = U_DIM * U_DIM;
    const int SU = IN_DIM * U_DIM;
    if (i < UU) {
        float s = sigma[i] * L2E;
        sm2[i] = make_float2(s, mu[i] * s);
        wep[i] = W[i] * erev[i];
    } else if (i < UU + SU) {
        int j = i - UU;
        float s = ssig[j] * L2E;
        float w = sW[j];
        sf4[j] = make_float4(s, smu[j] * s, w * serev[j], w);
    }
}

// ---------- sensory sums ----------
// tile 4 rows x 32 u; 256 thr = 4 waves; wave halves -> 8 strips x 32 i
__global__ __launch_bounds__(256, 8) void k_sensory(
    const float* __restrict__ inputs, const float* __restrict__ input_w,
    const float* __restrict__ input_b, const float4* __restrict__ sf4,
    float* __restrict__ wnum_s, float* __restrict__ wden_s) {
    __shared__ __align__(16) float xs[4 * IN_DIM];   // 4 KB
    __shared__ float red_n[4 * 4 * 32];              // 2 KB
    __shared__ float red_d[4 * 4 * 32];              // 2 KB
    const int tid = threadIdx.x;
    const int b0 = blockIdx.x * 4;
    const int u0 = blockIdx.y * 32;

    {   // stage x = in*w + b : 1024 floats = 256 float4, one per thread
        const int r = tid >> 6, c = tid & 63;
        float4 in4 = reinterpret_cast<const float4*>(inputs + (size_t)(b0 + r) * IN_DIM)[c];
        float4 iw4 = reinterpret_cast<const float4*>(input_w)[c];
        float4 ib4 = reinterpret_cast<const float4*>(input_b)[c];
        float4 x4 = make_float4(fmaf(in4.x, iw4.x, ib4.x), fmaf(in4.y, iw4.y, ib4.y),
                                fmaf(in4.z, iw4.z, ib4.z), fmaf(in4.w, iw4.w, ib4.w));
        reinterpret_cast<float4*>(xs)[tid] = x4;
    }
    __syncthreads();

    const int lane = tid & 63;
    const int w = tid >> 6;            // wave 0..3
    const int ulh = lane & 31;
    const int ih = lane >> 5;
    const int strip = w * 2 + ih;      // 0..7
    const int u = u0 + ulh;
    const int i0 = strip * 32;

    float nacc[4] = {0.f, 0.f, 0.f, 0.f};
    float dacc[4] = {0.f, 0.f, 0.f, 0.f};

    for (int ic = 0; ic < 32; ic += 4) {
        const int i = i0 + ic;
        float4 q0 = sf4[(i + 0) * U_DIM + u];
        float4 q1 = sf4[(i + 1) * U_DIM + u];
        float4 q2 = sf4[(i + 2) * U_DIM + u];
        float4 q3 = sf4[(i + 3) * U_DIM + u];
        #pragma unroll
        for (int r = 0; r < 4; ++r) {
            const float4 x4 = *reinterpret_cast<const float4*>(&xs[r * IN_DIM + i]);
            {
                float e = __builtin_amdgcn_exp2f(fmaf(-q0.x, x4.x, q0.y));
                float p = __builtin_amdgcn_rcpf(1.f + e);
                nacc[r] = fmaf(q0.z, p, nacc[r]); dacc[r] = fmaf(q0.w, p, dacc[r]);
            }
            {
                float e = __builtin_amdgcn_exp2f(fmaf(-q1.x, x4.y, q1.y));
                float p = __builtin_amdgcn_rcpf(1.f + e);
                nacc[r] = fmaf(q1.z, p, nacc[r]); dacc[r] = fmaf(q1.w, p, dacc[r]);
            }
            {
                float e = __builtin_amdgcn_exp2f(fmaf(-q2.x, x4.z, q2.y));
                float p = __builtin_amdgcn_rcpf(1.f + e);
                nacc[r] = fmaf(q2.z, p, nacc[r]); dacc[r] = fmaf(q2.w, p, dacc[r]);
            }
            {
                float e = __builtin_amdgcn_exp2f(fmaf(-q3.x, x4.w, q3.y));
                float p = __builtin_amdgcn_rcpf(1.f + e);
                nacc[r] = fmaf(q3.z, p, nacc[r]); dacc[r] = fmaf(q3.w, p, dacc[r]);
            }
        }
    }

    #pragma unroll
    for (int r = 0; r < 4; ++r) {
        nacc[r] += __shfl_xor(nacc[r], 32);
        dacc[r] += __shfl_xor(dacc[r], 32);
    }
    if (lane < 32) {
        #pragma unroll
        for (int r = 0; r < 4; ++r) {
            red_n[(w * 4 + r) * 32 + ulh] = nacc[r];
            red_d[(w * 4 + r) * 32 + ulh] = dacc[r];
        }
    }
    __syncthreads();
    if (tid < 4 * 32) {
        const int r = tid >> 5, uu = tid & 31;
        float n = 0.f, d = 0.f;
        #pragma unroll
        for (int s = 0; s < 4; ++s) {
            n += red_n[(s * 4 + r) * 32 + uu];
            d += red_d[(s * 4 + r) * 32 + uu];
        }
        wnum_s[(b0 + r) * U_DIM + (u0 + uu)] = n;
        wden_s[(b0 + r) * U_DIM + (u0 + uu)] = d;
    }
}

// ---------- one ODE unfold ----------
// tile 4 rows x 32 u; 256 thr = 4 waves; wave halves -> 8 strips x 64 i.
// Plain hw exp2 + hw rcp (2 trans/elem) — proven fastest form (210 us config),
// regeometried for 2048 blocks = 8 blocks/CU = 32 waves/CU.
__global__ __launch_bounds__(256, 8) void k_unfold(
    const float* __restrict__ vin,
    const float2* __restrict__ sm2, const float* __restrict__ wep,
    const float* __restrict__ wnum_s, const float* __restrict__ wden_s,
    const float* __restrict__ vleak, const float* __restrict__ gleak,
    const float* __restrict__ cm, float* __restrict__ vout) {
    __shared__ __align__(16) float vs[4 * U_DIM];    // 8 KB
    __shared__ float red_n[4 * 4 * 32];              // 2 KB
    __shared__ float red_d[4 * 4 * 32];              // 2 KB
    const int tid = threadIdx.x;
    const int b0 = blockIdx.x * 4;
    const int u0 = blockIdx.y * 32;

    // stage 4 rows of v: 2048 floats = 512 float4, 2 per thread
    #pragma unroll
    for (int k = 0; k < 2; ++k) {
        int idx = tid + k * 256;
        reinterpret_cast<float4*>(vs)[idx] =
            reinterpret_cast<const float4*>(vin + (size_t)b0 * U_DIM)[idx];
    }
    __syncthreads();

    const int lane = tid & 63;
    const int w = tid >> 6;            // wave 0..3
    const int ulh = lane & 31;
    const int ih = lane >> 5;
    const int strip = w * 2 + ih;      // 0..7
    const int u = u0 + ulh;
    const int i0 = strip * 64;

    float nacc[4] = {0.f, 0.f, 0.f, 0.f};
    float dacc[4] = {0.f, 0.f, 0.f, 0.f};

    for (int ic = 0; ic < 64; ic += 4) {
        const int i = i0 + ic;
        float2 q0 = sm2[(i + 0) * U_DIM + u];
        float2 q1 = sm2[(i + 1) * U_DIM + u];
        float2 q2 = sm2[(i + 2) * U_DIM + u];
        float2 q3 = sm2[(i + 3) * U_DIM + u];
        float we0 = wep[(i + 0) * U_DIM + u];
        float we1 = wep[(i + 1) * U_DIM + u];
        float we2 = wep[(i + 2) * U_DIM + u];
        float we3 = wep[(i + 3) * U_DIM + u];
        float w0 = fabsf(we0), w1 = fabsf(we1), w2 = fabsf(we2), w3 = fabsf(we3);
        #pragma unroll
        for (int r = 0; r < 4; ++r) {
            const float4 v4 = *reinterpret_cast<const float4*>(&vs[r * U_DIM + i]);
            {
                float e = __builtin_amdgcn_exp2f(fmaf(-q0.x, v4.x, q0.y));
                float p = __builtin_amdgcn_rcpf(1.f + e);
                nacc[r] = fmaf(we0, p, nacc[r]); dacc[r] = fmaf(w0, p, dacc[r]);
            }
            {
                float e = __builtin_amdgcn_exp2f(fmaf(-q1.x, v4.y, q1.y));
                float p = __builtin_amdgcn_rcpf(1.f + e);
                nacc[r] = fmaf(we1, p, nacc[r]); dacc[r] = fmaf(w1, p, dacc[r]);
            }
            {
                float e = __builtin_amdgcn_exp2f(fmaf(-q2.x, v4.z, q2.y));
                float p = __builtin_amdgcn_rcpf(1.f + e);
                nacc[r] = fmaf(we2, p, nacc[r]); dacc[r] = fmaf(w2, p, dacc[r]);
            }
            {
                float e = __builtin_amdgcn_exp2f(fmaf(-q3.x, v4.w, q3.y));
                float p = __builtin_amdgcn_rcpf(1.f + e);
                nacc[r] = fmaf(we3, p, nacc[r]); dacc[r] = fmaf(w3, p, dacc[r]);
            }
        }
    }

    #pragma unroll
    for (int r = 0; r < 4; ++r) {
        nacc[r] += __shfl_xor(nacc[r], 32);
        dacc[r] += __shfl_xor(dacc[r], 32);
    }
    if (lane < 32) {
        #pragma unroll
        for (int r = 0; r < 4; ++r) {
            red_n[(w * 4 + r) * 32 + ulh] = nacc[r];
            red_d[(w * 4 + r) * 32 + ulh] = dacc[r];
        }
    }
    __syncthreads();
    if (tid < 4 * 32) {
        const int r = tid >> 5, uu = tid & 31;
        float n = 0.f, d = 0.f;
        #pragma unroll
        for (int s = 0; s < 4; ++s) {
            n += red_n[(s * 4 + r) * 32 + uu];
            d += red_d[(s * 4 + r) * 32 + uu];
        }
        const int gu = u0 + uu, gb = b0 + r;
        float vold = vs[r * U_DIM + gu];
        float gl = gleak[gu], c = cm[gu];
        float num = fmaf(c, vold, fmaf(gl, vleak[gu], n + wnum_s[gb * U_DIM + gu]));
        float den = c + gl + d + wden_s[gb * U_DIM + gu];
        vout[gb * U_DIM + gu] = num * __builtin_amdgcn_rcpf(den);
    }
}

// ---------- fallback (tiny ws): one block per batch row ----------
__global__ __launch_bounds__(512) void k_mono(
    const float* __restrict__ inputs, const float* __restrict__ state,
    const float* __restrict__ input_w, const float* __restrict__ input_b,
    const float* __restrict__ smu, const float* __restrict__ ssig,
    const float* __restrict__ sW, const float* __restrict__ serev,
    const float* __restrict__ mu, const float* __restrict__ sigma,
    const float* __restrict__ W, const float* __restrict__ erev,
    const float* __restrict__ vleak, const float* __restrict__ gleak,
    const float* __restrict__ cm, float* __restrict__ out) {
    __shared__ float xs[IN_DIM];
    __shared__ float vsh[U_DIM];
    const int b = blockIdx.x, u = threadIdx.x;
    if (u < IN_DIM) xs[u] = fmaf(inputs[b * IN_DIM + u], input_w[u], input_b[u]);
    vsh[u] = state[b * U_DIM + u];
    __syncthreads();
    float ns = 0.f, ds = 0.f;
    for (int i = 0; i < IN_DIM; ++i) {
        int pi = i * U_DIM + u;
        float e = __builtin_amdgcn_exp2f((smu[pi] - xs[i]) * (ssig[pi] * L2E));
        float p = __builtin_amdgcn_rcpf(1.f + e);
        float a = sW[pi] * p;
        ns = fmaf(a, serev[pi], ns);
        ds += a;
    }
    const float c = cm[u], gl = gleak[u], glvl = gl * vleak[u];
    for (int t = 0; t < 6; ++t) {
        float n = ns, d = ds;
        for (int i = 0; i < U_DIM; ++i) {
            int pi = i * U_DIM + u;
            float e = __builtin_amdgcn_exp2f((mu[pi] - vsh[i]) * (sigma[pi] * L2E));
            float p = __builtin_amdgcn_rcpf(1.f + e);
            float a = W[pi] * p;
            n = fmaf(a, erev[pi], n);
            d += a;
        }
        float vn = (fmaf(c, vsh[u], glvl) + n) / (c + gl + d);
        __syncthreads();
        vsh[u] = vn;
        __syncthreads();
    }
    out[b * U_DIM + u] = vsh[u];
}

extern "C" void kernel_launch(void* const* d_in, const int* in_sizes, int n_in,
                              void* d_out, int out_size, void* d_ws, size_t ws_size,
                              hipStream_t stream) {
    const float* inputs  = (const float*)d_in[0];
    const float* state   = (const float*)d_in[1];
    const float* input_w = (const float*)d_in[2];
    const float* input_b = (const float*)d_in[3];
    const float* smu     = (const float*)d_in[4];
    const float* ssig    = (const float*)d_in[5];
    const float* sW      = (const float*)d_in[6];
    const float* serev   = (const float*)d_in[7];
    const float* mu      = (const float*)d_in[8];
    const float* sigma   = (const float*)d_in[9];
    const float* W       = (const float*)d_in[10];
    const float* erev    = (const float*)d_in[11];
    const float* vleak   = (const float*)d_in[12];
    const float* gleak   = (const float*)d_in[13];
    const float* cm      = (const float*)d_in[14];
    float* out = (float*)d_out;

    const int B = in_sizes[1] / U_DIM;   // 512
    const size_t BU = (size_t)B * U_DIM;
    const size_t UU = (size_t)U_DIM * U_DIM;
    const size_t SU = (size_t)IN_DIM * U_DIM;
    const size_t need = (3 * BU + 3 * UU + 4 * SU) * sizeof(float);

    if (ws_size >= need) {
        float* f      = (float*)d_ws;
        float* wnum_s = f;
        float* wden_s = f + BU;
        float* vbuf   = f + 2 * BU;
        float2* sm2   = (float2*)(f + 3 * BU);
        float* wep    = f + 3 * BU + 2 * UU;
        float4* sf4   = (float4*)(f + 3 * BU + 3 * UU);

        const int nfuse = (int)(UU + SU);
        k_fuse<<<(nfuse + 255) / 256, 256, 0, stream>>>(mu, sigma, W, erev,
                                                        smu, ssig, sW, serev,
                                                        sm2, wep, sf4);
        dim3 sgrid(B / 4, U_DIM / 32);   // 128 x 16 = 2048 blocks
        k_sensory<<<sgrid, 256, 0, stream>>>(inputs, input_w, input_b, sf4, wnum_s, wden_s);
        dim3 ugrid(B / 4, U_DIM / 32);   // 128 x 16 = 2048 blocks
        const float* vin = state;
        float* pong[2] = { vbuf, out };  // ends on out after 6 steps
        for (int t = 0; t < 6; ++t) {
            float* vo = pong[t & 1];
            k_unfold<<<ugrid, 256, 0, stream>>>(vin, sm2, wep, wnum_s, wden_s,
                                                vleak, gleak, cm, vo);
            vin = vo;
        }
    } else {
        k_mono<<<B, U_DIM, 0, stream>>>(inputs, state, input_w, input_b,
                                        smu, ssig, sW, serev, mu, sigma, W, erev,
                                        vleak, gleak, cm, out);
    }
}

// Round 8
// 206.881 us; speedup vs baseline: 1.4831x; 1.1010x over previous
//
#include <hip/hip_runtime.h>

#define IN_DIM 256
#define U_DIM  512
#define L2E    1.44269504088896340736f

typedef float f32x2 __attribute__((ext_vector_type(2)));
typedef float f32x4 __attribute__((ext_vector_type(4)));

__device__ __forceinline__ f32x2 vfma2(f32x2 a, f32x2 b, f32x2 c) {
    return __builtin_elementwise_fma(a, b, c);
}

// ---------- prefuse params into i-pair-packed float4s ----------
// rp4[pr*U+u] = (-sg_{2pr}, -sg_{2pr+1}, ms_{2pr}, ms_{2pr+1})   sg=sigma*l2e, ms=mu*sigma*l2e
// wp4[pr*U+u] = (we_{2pr}, we_{2pr+1}, w_{2pr}, w_{2pr+1})       we=W*erev
__global__ void k_fuse(const float* __restrict__ mu, const float* __restrict__ sigma,
                       const float* __restrict__ W, const float* __restrict__ erev,
                       const float* __restrict__ smu, const float* __restrict__ ssig,
                       const float* __restrict__ sW, const float* __restrict__ serev,
                       f32x4* __restrict__ rp4, f32x4* __restrict__ wp4,
                       f32x4* __restrict__ sp4, f32x4* __restrict__ swp4) {
    const int NR = (U_DIM / 2) * U_DIM;
    const int NS = (IN_DIM / 2) * U_DIM;
    int t = blockIdx.x * blockDim.x + threadIdx.x;
    if (t < NR) {
        const int u = t & (U_DIM - 1);
        const int pr = t >> 9;
        const int a = (2 * pr) * U_DIM + u, b = (2 * pr + 1) * U_DIM + u;
        float s0 = sigma[a] * L2E, s1 = sigma[b] * L2E;
        float w0 = W[a], w1 = W[b];
        rp4[t] = (f32x4){ -s0, -s1, mu[a] * s0, mu[b] * s1 };
        wp4[t] = (f32x4){ w0 * erev[a], w1 * erev[b], w0, w1 };
    } else if (t < NR + NS) {
        const int j = t - NR;
        const int u = j & (U_DIM - 1);
        const int pr = j >> 9;
        const int a = (2 * pr) * U_DIM + u, b = (2 * pr + 1) * U_DIM + u;
        float s0 = ssig[a] * L2E, s1 = ssig[b] * L2E;
        float w0 = sW[a], w1 = sW[b];
        sp4[j] = (f32x4){ -s0, -s1, smu[a] * s0, smu[b] * s1 };
        swp4[j] = (f32x4){ w0 * serev[a], w1 * serev[b], w0, w1 };
    }
}

// pair-step: 2 elements, 1 pk_fma(arg) + 2 exp2 + 1 pk_add + 2 rcp + 2 pk_fma(acc)
#define PAIR_STEP(Q, WD, VP, NA, DA)                                               \
    {                                                                              \
        f32x2 t_ = vfma2((Q).xy, (VP), (Q).zw);                                    \
        f32x2 e_;                                                                  \
        e_.x = __builtin_amdgcn_exp2f(t_.x);                                       \
        e_.y = __builtin_amdgcn_exp2f(t_.y);                                       \
        f32x2 d_ = e_ + (f32x2)(1.f);                                              \
        f32x2 p_;                                                                  \
        p_.x = __builtin_amdgcn_rcpf(d_.x);                                        \
        p_.y = __builtin_amdgcn_rcpf(d_.y);                                        \
        (NA) = vfma2((WD).xy, p_, (NA));                                           \
        (DA) = vfma2((WD).zw, p_, (DA));                                           \
    }

// ---------- sensory sums ----------
// tile 8 rows x 32 u; 512 thr = 8 waves; wave halves -> 16 strips x 16 i
__global__ __launch_bounds__(512, 4) void k_sensory(
    const float* __restrict__ inputs, const float* __restrict__ input_w,
    const float* __restrict__ input_b,
    const f32x4* __restrict__ sp4, const f32x4* __restrict__ swp4,
    float* __restrict__ wnum_s, float* __restrict__ wden_s) {
    __shared__ __align__(16) float xs[8 * IN_DIM];   // [r][i] row-major, 8 KB
    __shared__ float red_n[8 * 8 * 32];              // 8 KB
    __shared__ float red_d[8 * 8 * 32];              // 8 KB
    const int tid = threadIdx.x;
    const int b0 = blockIdx.x * 8;
    const int u0 = blockIdx.y * 32;

    #pragma unroll
    for (int k = 0; k < 4; ++k) {
        int idx = tid + k * 512;
        int r = idx >> 8, i = idx & 255;
        xs[idx] = fmaf(inputs[(b0 + r) * IN_DIM + i], input_w[i], input_b[i]);
    }
    __syncthreads();

    const int lane = tid & 63;
    const int w = tid >> 6;
    const int ulh = lane & 31;
    const int ih = lane >> 5;
    const int strip = w * 2 + ih;        // 0..15
    const int u = u0 + ulh;
    const int i0 = strip * 16;

    f32x2 nacc[8], dacc[8];
    #pragma unroll
    for (int r = 0; r < 8; ++r) { nacc[r] = (f32x2)(0.f); dacc[r] = (f32x2)(0.f); }

    for (int ic = 0; ic < 16; ic += 4) {
        const int i = i0 + ic;
        const int pr = i >> 1;
        f32x4 q0 = sp4[(pr + 0) * U_DIM + u];
        f32x4 q1 = sp4[(pr + 1) * U_DIM + u];
        f32x4 w0 = swp4[(pr + 0) * U_DIM + u];
        f32x4 w1 = swp4[(pr + 1) * U_DIM + u];
        #pragma unroll
        for (int r = 0; r < 8; ++r) {
            const f32x4 v4 = *reinterpret_cast<const f32x4*>(&xs[r * IN_DIM + i]);
            PAIR_STEP(q0, w0, v4.xy, nacc[r], dacc[r])
            PAIR_STEP(q1, w1, v4.zw, nacc[r], dacc[r])
        }
    }

    float nf[8], df[8];
    #pragma unroll
    for (int r = 0; r < 8; ++r) {
        nf[r] = nacc[r].x + nacc[r].y;
        df[r] = dacc[r].x + dacc[r].y;
        nf[r] += __shfl_xor(nf[r], 32);
        df[r] += __shfl_xor(df[r], 32);
    }
    if (lane < 32) {
        #pragma unroll
        for (int r = 0; r < 8; ++r) {
            red_n[(w * 8 + r) * 32 + ulh] = nf[r];
            red_d[(w * 8 + r) * 32 + ulh] = df[r];
        }
    }
    __syncthreads();
    if (tid < 8 * 32) {
        const int r = tid >> 5, uu = tid & 31;
        float n = 0.f, d = 0.f;
        #pragma unroll
        for (int s = 0; s < 8; ++s) {
            n += red_n[(s * 8 + r) * 32 + uu];
            d += red_d[(s * 8 + r) * 32 + uu];
        }
        wnum_s[(b0 + r) * U_DIM + (u0 + uu)] = n;
        wden_s[(b0 + r) * U_DIM + (u0 + uu)] = d;
    }
}

// ---------- one ODE unfold ----------
// tile 8 rows x 32 u; 512 thr = 8 waves; wave halves -> 16 strips x 32 i.
// R4 geometry/staging (proven 210us) + VOP3P i-pair packing: 2 VALU + 2 trans per element.
__global__ __launch_bounds__(512, 4) void k_unfold(
    const float* __restrict__ vin,
    const f32x4* __restrict__ rp4, const f32x4* __restrict__ wp4,
    const float* __restrict__ wnum_s, const float* __restrict__ wden_s,
    const float* __restrict__ vleak, const float* __restrict__ gleak,
    const float* __restrict__ cm, float* __restrict__ vout) {
    __shared__ __align__(16) float vs[8 * U_DIM];    // [r][i] row-major, 16 KB
    __shared__ float red_n[8 * 8 * 32];              // 8 KB
    __shared__ float red_d[8 * 8 * 32];              // 8 KB
    const int tid = threadIdx.x;
    const int b0 = blockIdx.x * 8;
    const int u0 = blockIdx.y * 32;

    #pragma unroll
    for (int k = 0; k < 2; ++k) {
        int idx = tid + k * 512;
        reinterpret_cast<float4*>(vs)[idx] =
            reinterpret_cast<const float4*>(vin + (size_t)b0 * U_DIM)[idx];
    }
    __syncthreads();

    const int lane = tid & 63;
    const int w = tid >> 6;
    const int ulh = lane & 31;
    const int ih = lane >> 5;
    const int strip = w * 2 + ih;        // 0..15
    const int u = u0 + ulh;
    const int i0 = strip * 32;

    f32x2 nacc[8], dacc[8];
    #pragma unroll
    for (int r = 0; r < 8; ++r) { nacc[r] = (f32x2)(0.f); dacc[r] = (f32x2)(0.f); }

    for (int ic = 0; ic < 32; ic += 4) {
        const int i = i0 + ic;
        const int pr = i >> 1;
        f32x4 q0 = rp4[(pr + 0) * U_DIM + u];
        f32x4 q1 = rp4[(pr + 1) * U_DIM + u];
        f32x4 w0 = wp4[(pr + 0) * U_DIM + u];
        f32x4 w1 = wp4[(pr + 1) * U_DIM + u];
        #pragma unroll
        for (int r = 0; r < 8; ++r) {
            const f32x4 v4 = *reinterpret_cast<const f32x4*>(&vs[r * U_DIM + i]);
            PAIR_STEP(q0, w0, v4.xy, nacc[r], dacc[r])
            PAIR_STEP(q1, w1, v4.zw, nacc[r], dacc[r])
        }
    }

    float nf[8], df[8];
    #pragma unroll
    for (int r = 0; r < 8; ++r) {
        nf[r] = nacc[r].x + nacc[r].y;
        df[r] = dacc[r].x + dacc[r].y;
        nf[r] += __shfl_xor(nf[r], 32);
        df[r] += __shfl_xor(df[r], 32);
    }
    if (lane < 32) {
        #pragma unroll
        for (int r = 0; r < 8; ++r) {
            red_n[(w * 8 + r) * 32 + ulh] = nf[r];
            red_d[(w * 8 + r) * 32 + ulh] = df[r];
        }
    }
    __syncthreads();
    if (tid < 8 * 32) {
        const int r = tid >> 5, uu = tid & 31;
        float n = 0.f, d = 0.f;
        #pragma unroll
        for (int s = 0; s < 8; ++s) {
            n += red_n[(s * 8 + r) * 32 + uu];
            d += red_d[(s * 8 + r) * 32 + uu];
        }
        const int gu = u0 + uu, gb = b0 + r;
        float vold = vs[r * U_DIM + gu];
        float gl = gleak[gu], c = cm[gu];
        float num = fmaf(c, vold, fmaf(gl, vleak[gu], n + wnum_s[gb * U_DIM + gu]));
        float den = c + gl + d + wden_s[gb * U_DIM + gu];
        vout[gb * U_DIM + gu] = num * __builtin_amdgcn_rcpf(den);
    }
}

// ---------- fallback (tiny ws): one block per batch row ----------
__global__ __launch_bounds__(512) void k_mono(
    const float* __restrict__ inputs, const float* __restrict__ state,
    const float* __restrict__ input_w, const float* __restrict__ input_b,
    const float* __restrict__ smu, const float* __restrict__ ssig,
    const float* __restrict__ sW, const float* __restrict__ serev,
    const float* __restrict__ mu, const float* __restrict__ sigma,
    const float* __restrict__ W, const float* __restrict__ erev,
    const float* __restrict__ vleak, const float* __restrict__ gleak,
    const float* __restrict__ cm, float* __restrict__ out) {
    __shared__ float xs[IN_DIM];
    __shared__ float vsh[U_DIM];
    const int b = blockIdx.x, u = threadIdx.x;
    if (u < IN_DIM) xs[u] = fmaf(inputs[b * IN_DIM + u], input_w[u], input_b[u]);
    vsh[u] = state[b * U_DIM + u];
    __syncthreads();
    float ns = 0.f, ds = 0.f;
    for (int i = 0; i < IN_DIM; ++i) {
        int pi = i * U_DIM + u;
        float e = __builtin_amdgcn_exp2f((smu[pi] - xs[i]) * (ssig[pi] * L2E));
        float p = __builtin_amdgcn_rcpf(1.f + e);
        float a = sW[pi] * p;
        ns = fmaf(a, serev[pi], ns);
        ds += a;
    }
    const float c = cm[u], gl = gleak[u], glvl = gl * vleak[u];
    for (int t = 0; t < 6; ++t) {
        float n = ns, d = ds;
        for (int i = 0; i < U_DIM; ++i) {
            int pi = i * U_DIM + u;
            float e = __builtin_amdgcn_exp2f((mu[pi] - vsh[i]) * (sigma[pi] * L2E));
            float p = __builtin_amdgcn_rcpf(1.f + e);
            float a = W[pi] * p;
            n = fmaf(a, erev[pi], n);
            d += a;
        }
        float vn = (fmaf(c, vsh[u], glvl) + n) / (c + gl + d);
        __syncthreads();
        vsh[u] = vn;
        __syncthreads();
    }
    out[b * U_DIM + u] = vsh[u];
}

extern "C" void kernel_launch(void* const* d_in, const int* in_sizes, int n_in,
                              void* d_out, int out_size, void* d_ws, size_t ws_size,
                              hipStream_t stream) {
    const float* inputs  = (const float*)d_in[0];
    const float* state   = (const float*)d_in[1];
    const float* input_w = (const float*)d_in[2];
    const float* input_b = (const float*)d_in[3];
    const float* smu     = (const float*)d_in[4];
    const float* ssig    = (const float*)d_in[5];
    const float* sW      = (const float*)d_in[6];
    const float* serev   = (const float*)d_in[7];
    const float* mu      = (const float*)d_in[8];
    const float* sigma   = (const float*)d_in[9];
    const float* W       = (const float*)d_in[10];
    const float* erev    = (const float*)d_in[11];
    const float* vleak   = (const float*)d_in[12];
    const float* gleak   = (const float*)d_in[13];
    const float* cm      = (const float*)d_in[14];
    float* out = (float*)d_out;

    const int B = in_sizes[1] / U_DIM;   // 512
    const size_t BU = (size_t)B * U_DIM;
    const size_t UU = (size_t)U_DIM * U_DIM;
    const size_t SU = (size_t)IN_DIM * U_DIM;
    const size_t need = (3 * BU + 4 * UU + 4 * SU) * sizeof(float);

    if (ws_size >= need) {
        float* f      = (float*)d_ws;
        float* wnum_s = f;
        float* wden_s = f + BU;
        float* vbuf   = f + 2 * BU;
        f32x4* rp4    = (f32x4*)(f + 3 * BU);                 // 2*UU floats
        f32x4* wp4    = (f32x4*)(f + 3 * BU + 2 * UU);        // 2*UU floats
        f32x4* sp4    = (f32x4*)(f + 3 * BU + 4 * UU);        // 2*SU floats
        f32x4* swp4   = (f32x4*)(f + 3 * BU + 4 * UU + 2 * SU); // 2*SU floats

        const int nfuse = (int)(UU / 2 + SU / 2);
        k_fuse<<<(nfuse + 255) / 256, 256, 0, stream>>>(mu, sigma, W, erev,
                                                        smu, ssig, sW, serev,
                                                        rp4, wp4, sp4, swp4);
        dim3 grid(B / 8, U_DIM / 32);    // 64 x 16 = 1024 blocks
        k_sensory<<<grid, 512, 0, stream>>>(inputs, input_w, input_b, sp4, swp4,
                                            wnum_s, wden_s);
        const float* vin = state;
        float* pong[2] = { vbuf, out };  // ends on out after 6 steps
        for (int t = 0; t < 6; ++t) {
            float* vo = pong[t & 1];
            k_unfold<<<grid, 512, 0, stream>>>(vin, rp4, wp4, wnum_s, wden_s,
                                               vleak, gleak, cm, vo);
            vin = vo;
        }
    } else {
        k_mono<<<B, U_DIM, 0, stream>>>(inputs, state, input_w, input_b,
                                        smu, ssig, sW, serev, mu, sigma, W, erev,
                                        vleak, gleak, cm, out);
    }
}

// Round 9
// 206.727 us; speedup vs baseline: 1.4842x; 1.0007x over previous
//
#include <hip/hip_runtime.h>

#define IN_DIM 256
#define U_DIM  512
#define L2E    1.44269504088896340736f

typedef float f32x2 __attribute__((ext_vector_type(2)));
typedef float f32x4 __attribute__((ext_vector_type(4)));

__device__ __forceinline__ f32x2 vfma2(f32x2 a, f32x2 b, f32x2 c) {
    return __builtin_elementwise_fma(a, b, c);
}

// ---------- prefuse params into i-pair-packed float4s ----------
// rp4[pr*U+u] = (-sg_{2pr}, -sg_{2pr+1}, ms_{2pr}, ms_{2pr+1})   sg=sigma*l2e, ms=mu*sigma*l2e
// wp4[pr*U+u] = (we_{2pr}, we_{2pr+1}, w_{2pr}, w_{2pr+1})       we=W*erev
__global__ void k_fuse(const float* __restrict__ mu, const float* __restrict__ sigma,
                       const float* __restrict__ W, const float* __restrict__ erev,
                       const float* __restrict__ smu, const float* __restrict__ ssig,
                       const float* __restrict__ sW, const float* __restrict__ serev,
                       f32x4* __restrict__ rp4, f32x4* __restrict__ wp4,
                       f32x4* __restrict__ sp4, f32x4* __restrict__ swp4) {
    const int NR = (U_DIM / 2) * U_DIM;
    const int NS = (IN_DIM / 2) * U_DIM;
    int t = blockIdx.x * blockDim.x + threadIdx.x;
    if (t < NR) {
        const int u = t & (U_DIM - 1);
        const int pr = t >> 9;
        const int a = (2 * pr) * U_DIM + u, b = (2 * pr + 1) * U_DIM + u;
        float s0 = sigma[a] * L2E, s1 = sigma[b] * L2E;
        float w0 = W[a], w1 = W[b];
        rp4[t] = (f32x4){ -s0, -s1, mu[a] * s0, mu[b] * s1 };
        wp4[t] = (f32x4){ w0 * erev[a], w1 * erev[b], w0, w1 };
    } else if (t < NR + NS) {
        const int j = t - NR;
        const int u = j & (U_DIM - 1);
        const int pr = j >> 9;
        const int a = (2 * pr) * U_DIM + u, b = (2 * pr + 1) * U_DIM + u;
        float s0 = ssig[a] * L2E, s1 = ssig[b] * L2E;
        float w0 = sW[a], w1 = sW[b];
        sp4[j] = (f32x4){ -s0, -s1, smu[a] * s0, smu[b] * s1 };
        swp4[j] = (f32x4){ w0 * serev[a], w1 * serev[b], w0, w1 };
    }
}

// pair-step: 2 elements; hw exp2 + hw rcp (proven fastest decomposition)
#define PAIR_STEP(Q, WD, VP, NA, DA)                                               \
    {                                                                              \
        f32x2 t_ = vfma2((Q).xy, (VP), (Q).zw);                                    \
        f32x2 e_;                                                                  \
        e_.x = __builtin_amdgcn_exp2f(t_.x);                                       \
        e_.y = __builtin_amdgcn_exp2f(t_.y);                                       \
        f32x2 d_ = e_ + (f32x2)(1.f);                                              \
        f32x2 p_;                                                                  \
        p_.x = __builtin_amdgcn_rcpf(d_.x);                                        \
        p_.y = __builtin_amdgcn_rcpf(d_.y);                                        \
        (NA) = vfma2((WD).xy, p_, (NA));                                           \
        (DA) = vfma2((WD).zw, p_, (DA));                                           \
    }

// ---------- sensory sums ----------
// tile 8 rows x 32 u; 512 thr = 8 waves; wave halves -> 16 strips x 16 i
__global__ __launch_bounds__(512, 4) void k_sensory(
    const float* __restrict__ inputs, const float* __restrict__ input_w,
    const float* __restrict__ input_b,
    const f32x4* __restrict__ sp4, const f32x4* __restrict__ swp4,
    float* __restrict__ wnum_s, float* __restrict__ wden_s) {
    __shared__ __align__(16) float xs[8 * IN_DIM];   // [r][i] row-major, 8 KB
    __shared__ float red_n[8 * 8 * 32];              // 8 KB
    __shared__ float red_d[8 * 8 * 32];              // 8 KB
    const int tid = threadIdx.x;
    const int b0 = blockIdx.x * 8;
    const int u0 = blockIdx.y * 32;

    const int lane = tid & 63;
    const int w = tid >> 6;
    const int ulh = lane & 31;
    const int ih = lane >> 5;
    const int strip = w * 2 + ih;        // 0..15
    const int u = u0 + ulh;
    const int i0 = strip * 16;
    const int pr0 = i0 >> 1;

    const f32x4* __restrict__ rp = sp4 + u;
    const f32x4* __restrict__ wp = swp4 + u;

    // issue first param loads before the staging barrier
    f32x4 q0 = rp[(pr0 + 0) * U_DIM], q1 = rp[(pr0 + 1) * U_DIM];
    f32x4 x0 = wp[(pr0 + 0) * U_DIM], x1 = wp[(pr0 + 1) * U_DIM];

    {   // stage x = in*w + b : 2048 floats = 512 float4, one per thread
        const int r = tid >> 6, c = tid & 63;
        float4 in4 = reinterpret_cast<const float4*>(inputs + (size_t)(b0 + r) * IN_DIM)[c];
        float4 iw4 = reinterpret_cast<const float4*>(input_w)[c];
        float4 ib4 = reinterpret_cast<const float4*>(input_b)[c];
        float4 v = make_float4(fmaf(in4.x, iw4.x, ib4.x), fmaf(in4.y, iw4.y, ib4.y),
                               fmaf(in4.z, iw4.z, ib4.z), fmaf(in4.w, iw4.w, ib4.w));
        reinterpret_cast<float4*>(xs)[tid] = v;
    }
    __syncthreads();

    f32x2 nacc[8], dacc[8];
    #pragma unroll
    for (int r = 0; r < 8; ++r) { nacc[r] = (f32x2)(0.f); dacc[r] = (f32x2)(0.f); }

    #pragma unroll
    for (int ic = 0; ic < 16; ic += 4) {
        // prefetch next iteration's params (clamped index keeps it in-bounds; dead on last iter)
        const int prn = (ic < 12) ? ((i0 + ic + 4) >> 1) : pr0;
        f32x4 nq0 = rp[(prn + 0) * U_DIM], nq1 = rp[(prn + 1) * U_DIM];
        f32x4 nx0 = wp[(prn + 0) * U_DIM], nx1 = wp[(prn + 1) * U_DIM];

        const int i = i0 + ic;
        #pragma unroll
        for (int r = 0; r < 8; ++r) {
            const f32x4 v4 = *reinterpret_cast<const f32x4*>(&xs[r * IN_DIM + i]);
            PAIR_STEP(q0, x0, v4.xy, nacc[r], dacc[r])
            PAIR_STEP(q1, x1, v4.zw, nacc[r], dacc[r])
        }
        q0 = nq0; q1 = nq1; x0 = nx0; x1 = nx1;
    }

    float nf[8], df[8];
    #pragma unroll
    for (int r = 0; r < 8; ++r) {
        nf[r] = nacc[r].x + nacc[r].y;
        df[r] = dacc[r].x + dacc[r].y;
        nf[r] += __shfl_xor(nf[r], 32);
        df[r] += __shfl_xor(df[r], 32);
    }
    if (lane < 32) {
        #pragma unroll
        for (int r = 0; r < 8; ++r) {
            red_n[(w * 8 + r) * 32 + ulh] = nf[r];
            red_d[(w * 8 + r) * 32 + ulh] = df[r];
        }
    }
    __syncthreads();
    if (tid < 8 * 32) {
        const int r = tid >> 5, uu = tid & 31;
        float n = 0.f, d = 0.f;
        #pragma unroll
        for (int s = 0; s < 8; ++s) {
            n += red_n[(s * 8 + r) * 32 + uu];
            d += red_d[(s * 8 + r) * 32 + uu];
        }
        wnum_s[(b0 + r) * U_DIM + (u0 + uu)] = n;
        wden_s[(b0 + r) * U_DIM + (u0 + uu)] = d;
    }
}

// ---------- one ODE unfold ----------
// tile 8 rows x 32 u; 512 thr = 8 waves; wave halves -> 16 strips x 32 i.
// R8 geometry + software-prefetched params (loads issued one full iter ahead).
__global__ __launch_bounds__(512, 4) void k_unfold(
    const float* __restrict__ vin,
    const f32x4* __restrict__ rp4, const f32x4* __restrict__ wp4,
    const float* __restrict__ wnum_s, const float* __restrict__ wden_s,
    const float* __restrict__ vleak, const float* __restrict__ gleak,
    const float* __restrict__ cm, float* __restrict__ vout) {
    __shared__ __align__(16) float vs[8 * U_DIM];    // [r][i] row-major, 16 KB
    __shared__ float red_n[8 * 8 * 32];              // 8 KB
    __shared__ float red_d[8 * 8 * 32];              // 8 KB
    const int tid = threadIdx.x;
    const int b0 = blockIdx.x * 8;
    const int u0 = blockIdx.y * 32;

    const int lane = tid & 63;
    const int w = tid >> 6;
    const int ulh = lane & 31;
    const int ih = lane >> 5;
    const int strip = w * 2 + ih;        // 0..15
    const int u = u0 + ulh;
    const int i0 = strip * 32;
    const int pr0 = i0 >> 1;

    const f32x4* __restrict__ rp = rp4 + u;
    const f32x4* __restrict__ wp = wp4 + u;

    // issue first param loads before staging barrier (fly during barrier wait)
    f32x4 q0 = rp[(pr0 + 0) * U_DIM], q1 = rp[(pr0 + 1) * U_DIM];
    f32x4 x0 = wp[(pr0 + 0) * U_DIM], x1 = wp[(pr0 + 1) * U_DIM];

    #pragma unroll
    for (int k = 0; k < 2; ++k) {
        int idx = tid + k * 512;
        reinterpret_cast<float4*>(vs)[idx] =
            reinterpret_cast<const float4*>(vin + (size_t)b0 * U_DIM)[idx];
    }
    __syncthreads();

    f32x2 nacc[8], dacc[8];
    #pragma unroll
    for (int r = 0; r < 8; ++r) { nacc[r] = (f32x2)(0.f); dacc[r] = (f32x2)(0.f); }

    #pragma unroll
    for (int ic = 0; ic < 32; ic += 4) {
        // prefetch next iteration's params
        const int prn = (ic < 28) ? ((i0 + ic + 4) >> 1) : pr0;
        f32x4 nq0 = rp[(prn + 0) * U_DIM], nq1 = rp[(prn + 1) * U_DIM];
        f32x4 nx0 = wp[(prn + 0) * U_DIM], nx1 = wp[(prn + 1) * U_DIM];

        const int i = i0 + ic;
        #pragma unroll
        for (int r = 0; r < 8; ++r) {
            const f32x4 v4 = *reinterpret_cast<const f32x4*>(&vs[r * U_DIM + i]);
            PAIR_STEP(q0, x0, v4.xy, nacc[r], dacc[r])
            PAIR_STEP(q1, x1, v4.zw, nacc[r], dacc[r])
        }
        q0 = nq0; q1 = nq1; x0 = nx0; x1 = nx1;
    }

    float nf[8], df[8];
    #pragma unroll
    for (int r = 0; r < 8; ++r) {
        nf[r] = nacc[r].x + nacc[r].y;
        df[r] = dacc[r].x + dacc[r].y;
        nf[r] += __shfl_xor(nf[r], 32);
        df[r] += __shfl_xor(df[r], 32);
    }
    if (lane < 32) {
        #pragma unroll
        for (int r = 0; r < 8; ++r) {
            red_n[(w * 8 + r) * 32 + ulh] = nf[r];
            red_d[(w * 8 + r) * 32 + ulh] = df[r];
        }
    }
    __syncthreads();
    if (tid < 8 * 32) {
        const int r = tid >> 5, uu = tid & 31;
        float n = 0.f, d = 0.f;
        #pragma unroll
        for (int s = 0; s < 8; ++s) {
            n += red_n[(s * 8 + r) * 32 + uu];
            d += red_d[(s * 8 + r) * 32 + uu];
        }
        const int gu = u0 + uu, gb = b0 + r;
        float vold = vs[r * U_DIM + gu];
        float gl = gleak[gu], c = cm[gu];
        float num = fmaf(c, vold, fmaf(gl, vleak[gu], n + wnum_s[gb * U_DIM + gu]));
        float den = c + gl + d + wden_s[gb * U_DIM + gu];
        vout[gb * U_DIM + gu] = num * __builtin_amdgcn_rcpf(den);
    }
}

// ---------- fallback (tiny ws): one block per batch row ----------
__global__ __launch_bounds__(512) void k_mono(
    const float* __restrict__ inputs, const float* __restrict__ state,
    const float* __restrict__ input_w, const float* __restrict__ input_b,
    const float* __restrict__ smu, const float* __restrict__ ssig,
    const float* __restrict__ sW, const float* __restrict__ serev,
    const float* __restrict__ mu, const float* __restrict__ sigma,
    const float* __restrict__ W, const float* __restrict__ erev,
    const float* __restrict__ vleak, const float* __restrict__ gleak,
    const float* __restrict__ cm, float* __restrict__ out) {
    __shared__ float xs[IN_DIM];
    __shared__ float vsh[U_DIM];
    const int b = blockIdx.x, u = threadIdx.x;
    if (u < IN_DIM) xs[u] = fmaf(inputs[b * IN_DIM + u], input_w[u], input_b[u]);
    vsh[u] = state[b * U_DIM + u];
    __syncthreads();
    float ns = 0.f, ds = 0.f;
    for (int i = 0; i < IN_DIM; ++i) {
        int pi = i * U_DIM + u;
        float e = __builtin_amdgcn_exp2f((smu[pi] - xs[i]) * (ssig[pi] * L2E));
        float p = __builtin_amdgcn_rcpf(1.f + e);
        float a = sW[pi] * p;
        ns = fmaf(a, serev[pi], ns);
        ds += a;
    }
    const float c = cm[u], gl = gleak[u], glvl = gl * vleak[u];
    for (int t = 0; t < 6; ++t) {
        float n = ns, d = ds;
        for (int i = 0; i < U_DIM; ++i) {
            int pi = i * U_DIM + u;
            float e = __builtin_amdgcn_exp2f((mu[pi] - vsh[i]) * (sigma[pi] * L2E));
            float p = __builtin_amdgcn_rcpf(1.f + e);
            float a = W[pi] * p;
            n = fmaf(a, erev[pi], n);
            d += a;
        }
        float vn = (fmaf(c, vsh[u], glvl) + n) / (c + gl + d);
        __syncthreads();
        vsh[u] = vn;
        __syncthreads();
    }
    out[b * U_DIM + u] = vsh[u];
}

extern "C" void kernel_launch(void* const* d_in, const int* in_sizes, int n_in,
                              void* d_out, int out_size, void* d_ws, size_t ws_size,
                              hipStream_t stream) {
    const float* inputs  = (const float*)d_in[0];
    const float* state   = (const float*)d_in[1];
    const float* input_w = (const float*)d_in[2];
    const float* input_b = (const float*)d_in[3];
    const float* smu     = (const float*)d_in[4];
    const float* ssig    = (const float*)d_in[5];
    const float* sW      = (const float*)d_in[6];
    const float* serev   = (const float*)d_in[7];
    const float* mu      = (const float*)d_in[8];
    const float* sigma   = (const float*)d_in[9];
    const float* W       = (const float*)d_in[10];
    const float* erev    = (const float*)d_in[11];
    const float* vleak   = (const float*)d_in[12];
    const float* gleak   = (const float*)d_in[13];
    const float* cm      = (const float*)d_in[14];
    float* out = (float*)d_out;

    const int B = in_sizes[1] / U_DIM;   // 512
    const size_t BU = (size_t)B * U_DIM;
    const size_t UU = (size_t)U_DIM * U_DIM;
    const size_t SU = (size_t)IN_DIM * U_DIM;
    const size_t need = (3 * BU + 4 * UU + 4 * SU) * sizeof(float);

    if (ws_size >= need) {
        float* f      = (float*)d_ws;
        float* wnum_s = f;
        float* wden_s = f + BU;
        float* vbuf   = f + 2 * BU;
        f32x4* rp4    = (f32x4*)(f + 3 * BU);                 // 2*UU floats
        f32x4* wp4    = (f32x4*)(f + 3 * BU + 2 * UU);        // 2*UU floats
        f32x4* sp4    = (f32x4*)(f + 3 * BU + 4 * UU);        // 2*SU floats
        f32x4* swp4   = (f32x4*)(f + 3 * BU + 4 * UU + 2 * SU); // 2*SU floats

        const int nfuse = (int)(UU / 2 + SU / 2);
        k_fuse<<<(nfuse + 255) / 256, 256, 0, stream>>>(mu, sigma, W, erev,
                                                        smu, ssig, sW, serev,
                                                        rp4, wp4, sp4, swp4);
        dim3 grid(B / 8, U_DIM / 32);    // 64 x 16 = 1024 blocks
        k_sensory<<<grid, 512, 0, stream>>>(inputs, input_w, input_b, sp4, swp4,
                                            wnum_s, wden_s);
        const float* vin = state;
        float* pong[2] = { vbuf, out };  // ends on out after 6 steps
        for (int t = 0; t < 6; ++t) {
            float* vo = pong[t & 1];
            k_unfold<<<grid, 512, 0, stream>>>(vin, rp4, wp4, wnum_s, wden_s,
                                               vleak, gleak, cm, vo);
            vin = vo;
        }
    } else {
        k_mono<<<B, U_DIM, 0, stream>>>(inputs, state, input_w, input_b,
                                        smu, ssig, sW, serev, mu, sigma, W, erev,
                                        vleak, gleak, cm, out);
    }
}